// Round 2
// 306.063 us; speedup vs baseline: 1.1535x; 1.1535x over previous
//
#include <hip/hip_runtime.h>

// BatchSplitFF: DM=1024, NE=16, ES=4 (NES=64 expert pairs), ESZ=64,
// BATCH*SEQ = 8*2048 tokens -> 1024 groups of 16 tokens.
#define DM   1024
#define NES  64
#define ESZ  64
#define NG   1024
#define TOK  16

typedef __bf16 bf16;
typedef __bf16 bf16x4 __attribute__((ext_vector_type(4)));
typedef __bf16 bf16x8 __attribute__((ext_vector_type(8)));
typedef float  f32x4  __attribute__((ext_vector_type(4)));

// async global->LDS, 16B per lane, LDS dest = wave-uniform base + lane*16
__device__ __forceinline__ void gld_lds16(const bf16* g, bf16* s) {
    __builtin_amdgcn_global_load_lds(
        (const __attribute__((address_space(1))) void*)g,
        (__attribute__((address_space(3))) void*)s, 16, 0, 0);
}

// ---------------- K0: transpose weights to bf16, MFMA-friendly layouts ----
// f1 [d][es][f] -> f1p bf16 [es][f][d]   f2 [es][f][d] -> f2t bf16 [es][d][f]
__global__ __launch_bounds__(256) void k0_transpose(const float* __restrict__ f1,
                                                    const float* __restrict__ f2,
                                                    bf16* __restrict__ f1p,
                                                    bf16* __restrict__ f2t) {
    __shared__ float tile[64 * 65];
    const int es = blockIdx.y, d0 = blockIdx.x * 64, tid = threadIdx.x;
    #pragma unroll
    for (int i = 0; i < 4; ++i) {
        int idx = i * 256 + tid; int r = idx >> 4, c4 = (idx & 15) * 4;
        float4 v = *(const float4*)(f1 + (size_t)(d0 + r) * 4096 + es * 64 + c4);
        tile[r * 65 + c4] = v.x; tile[r * 65 + c4 + 1] = v.y;
        tile[r * 65 + c4 + 2] = v.z; tile[r * 65 + c4 + 3] = v.w;
    }
    __syncthreads();
    #pragma unroll
    for (int i = 0; i < 2; ++i) {
        int idx = i * 256 + tid; int f = idx >> 3, dl0 = (idx & 7) * 8;
        bf16x8 o;
        #pragma unroll
        for (int j = 0; j < 8; ++j) o[j] = (bf16)tile[(dl0 + j) * 65 + f];
        *(bf16x8*)(f1p + (size_t)es * 65536 + f * 1024 + d0 + dl0) = o;
    }
    __syncthreads();
    #pragma unroll
    for (int i = 0; i < 4; ++i) {
        int idx = i * 256 + tid; int r = idx >> 4, c4 = (idx & 15) * 4;
        float4 v = *(const float4*)(f2 + (size_t)es * 65536 + r * 1024 + d0 + c4);
        tile[r * 65 + c4] = v.x; tile[r * 65 + c4 + 1] = v.y;
        tile[r * 65 + c4 + 2] = v.z; tile[r * 65 + c4 + 3] = v.w;
    }
    __syncthreads();
    #pragma unroll
    for (int i = 0; i < 2; ++i) {
        int idx = i * 256 + tid; int dl = idx >> 3, f0 = (idx & 7) * 8;
        bf16x8 o;
        #pragma unroll
        for (int j = 0; j < 8; ++j) o[j] = (bf16)tile[(f0 + j) * 65 + dl];
        *(bf16x8*)(f2t + (size_t)es * 65536 + (size_t)(d0 + dl) * 64 + f0) = o;
    }
}

// ---------------- K1: fp32 logits + argmax + sel nibble-pack ----------------
// Unchanged this round (bit-identical logits chain preserved).
__global__ __launch_bounds__(256) void k1_logits(const float* __restrict__ x,
                                                 const float* __restrict__ ctrl,
                                                 int* __restrict__ sel,
                                                 unsigned* __restrict__ selp) {
    __shared__ __align__(16) float xs[TOK * 132];   // row stride 132 (528B, 16B-mult)
    __shared__ float sl[TOK * NES];
    __shared__ int   st[NES];
    const int bg  = blockIdx.x;
    const int tid = threadIdx.x;
    const int es  = tid & 63;
    const int tq  = tid >> 6;            // wave 0..3 -> rows tq*4 .. tq*4+3
    const float* xg = x + (size_t)bg * (TOK * DM);
    const float* cp = ctrl + es;
    float acc[4] = {0.f, 0.f, 0.f, 0.f};
    for (int d0 = 0; d0 < DM; d0 += 128) {
        __syncthreads();
        #pragma unroll
        for (int c = 0; c < 2; ++c) {    // stage 16 x 128 chunk (coalesced)
            int idx = tid + c * 256;
            int tr  = idx >> 5;
            int c4  = (idx & 31) * 4;
            float4 v = *(const float4*)(xg + tr * DM + d0 + c4);
            *(float4*)(xs + tr * 132 + c4) = v;
        }
        __syncthreads();
        #pragma unroll 2
        for (int dl4 = 0; dl4 < 128; dl4 += 4) {
            float4 v0 = *(const float4*)(xs + (tq * 4 + 0) * 132 + dl4);
            float4 v1 = *(const float4*)(xs + (tq * 4 + 1) * 132 + dl4);
            float4 v2 = *(const float4*)(xs + (tq * 4 + 2) * 132 + dl4);
            float4 v3 = *(const float4*)(xs + (tq * 4 + 3) * 132 + dl4);
            float c0 = cp[(size_t)(d0 + dl4 + 0) * 64];
            float c1 = cp[(size_t)(d0 + dl4 + 1) * 64];
            float c2 = cp[(size_t)(d0 + dl4 + 2) * 64];
            float c3 = cp[(size_t)(d0 + dl4 + 3) * 64];
            acc[0] += v0.x * c0; acc[1] += v1.x * c0;
            acc[2] += v2.x * c0; acc[3] += v3.x * c0;
            acc[0] += v0.y * c1; acc[1] += v1.y * c1;
            acc[2] += v2.y * c1; acc[3] += v3.y * c1;
            acc[0] += v0.z * c2; acc[1] += v1.z * c2;
            acc[2] += v2.z * c2; acc[3] += v3.z * c2;
            acc[0] += v0.w * c3; acc[1] += v1.w * c3;
            acc[2] += v2.w * c3; acc[3] += v3.w * c3;
        }
    }
    #pragma unroll
    for (int i = 0; i < 4; ++i) {
        int t = tq * 4 + i;
        sl[t * NES + es] = acc[i] + (float)t * (1e-6f / 15.f);
    }
    __syncthreads();
    if (tid < NES) {
        float best = -1e30f; int bi = 0;
        #pragma unroll
        for (int t = 0; t < TOK; ++t) {
            float v = sl[t * NES + tid];
            if (v >= best) { best = v; bi = t; }   // >= : later t wins ties
        }
        sel[bg * NES + tid] = bi;
        st[tid] = bi;
    }
    __syncthreads();
    if (tid < 8) {   // pack 8 es per dword, 4-bit each
        unsigned p = 0;
        #pragma unroll
        for (int k = 0; k < 8; ++k) p |= (unsigned)st[tid * 8 + k] << (4 * k);
        selp[bg * 8 + tid] = p;
    }
}

// ---------------- K2: FFN1 (gather + GEMM + bias + relu) ----------------
__global__ __launch_bounds__(256) void k2_ffn1(const float* __restrict__ x,
                                               const bf16* __restrict__ f1p,
                                               const float* __restrict__ bias,
                                               const int* __restrict__ sel,
                                               bf16* __restrict__ inner) {
    __shared__ int  sel_s[128];
    __shared__ __align__(16) bf16 As[128 * 40];
    __shared__ __align__(16) bf16 Bs[64 * 40];
    const int es  = blockIdx.y;
    const int g0  = blockIdx.x * 128;
    const int tid = threadIdx.x;
    if (tid < 128) sel_s[tid] = sel[(g0 + tid) * 64 + es];
    __syncthreads();

    const int w = tid >> 6, l = tid & 63, quad = l >> 4, lr = l & 15;
    int tokrow[4];
    #pragma unroll
    for (int p = 0; p < 4; ++p) {
        int grow = p * 32 + (tid >> 3);
        tokrow[p] = (g0 + grow) * 16 + sel_s[grow];
    }
    const int c4 = (tid & 7) * 4;
    const int bf = tid >> 2, bd = (tid & 3) * 8;
    const bf16* f1es = f1p + (size_t)es * (DM * ESZ);

    f32x4 acc[2][4];
    #pragma unroll
    for (int mt = 0; mt < 2; ++mt)
        #pragma unroll
        for (int nt = 0; nt < 4; ++nt)
            acc[mt][nt] = (f32x4){0.f, 0.f, 0.f, 0.f};

    for (int k0 = 0; k0 < DM; k0 += 32) {
        #pragma unroll
        for (int p = 0; p < 4; ++p) {
            int grow = p * 32 + (tid >> 3);
            float4 v = *(const float4*)(x + (size_t)tokrow[p] * DM + k0 + c4);
            bf16x4 ob = {(bf16)v.x, (bf16)v.y, (bf16)v.z, (bf16)v.w};
            *(bf16x4*)(As + grow * 40 + c4) = ob;
        }
        {
            bf16x8 v = *(const bf16x8*)(f1es + bf * 1024 + k0 + bd);
            *(bf16x8*)(Bs + bf * 40 + bd) = v;
        }
        __syncthreads();
        bf16x8 av[2], bv[4];
        #pragma unroll
        for (int mt = 0; mt < 2; ++mt)
            av[mt] = *(const bf16x8*)(As + (w * 32 + mt * 16 + lr) * 40 + quad * 8);
        #pragma unroll
        for (int nt = 0; nt < 4; ++nt)
            bv[nt] = *(const bf16x8*)(Bs + (nt * 16 + lr) * 40 + quad * 8);
        #pragma unroll
        for (int mt = 0; mt < 2; ++mt)
            #pragma unroll
            for (int nt = 0; nt < 4; ++nt)
                acc[mt][nt] = __builtin_amdgcn_mfma_f32_16x16x32_bf16(
                    av[mt], bv[nt], acc[mt][nt], 0, 0, 0);
        __syncthreads();
    }
    bf16* innes = inner + (size_t)es * (NG * ESZ);
    #pragma unroll
    for (int mt = 0; mt < 2; ++mt)
        #pragma unroll
        for (int nt = 0; nt < 4; ++nt) {
            int f = nt * 16 + lr;
            float b = bias[es * 64 + f];
            #pragma unroll
            for (int r = 0; r < 4; ++r) {
                int grow = w * 32 + mt * 16 + quad * 4 + r;
                float v = acc[mt][nt][r] + b;
                v = v > 0.f ? v : 0.f;
                innes[(size_t)(g0 + grow) * 64 + f] = (bf16)v;
            }
        }
}

// ---------------- K3: FFN2 + un-permute scatter ----------------
// Round-3 structure: A/B tiles staged into LDS via global_load_lds width=16
// (each es-tile is 32 rows x 128 B = 4 KB CONTIGUOUS -> exactly 256 lanes x
// 16 B = one instruction per tile), double-buffered with COUNTED vmcnt(2)
// and raw s_barrier (stage for es+1 stays in flight across the whole
// iteration; never drained to 0 in the loop). This removes the 2x
// intra-block A/B duplication (waves now read fragments from LDS) and cuts
// per-iter VMEM from 16 cache loads to 4 DMA loads.
//
// Bank conflicts: tile rows are 128 B, so a linear layout would put all 16
// fragment rows on the same banks (8-way on ds_read_b128). Per rule #21
// (swizzle both-sides-or-neither with global_load_lds): LDS dest stays
// LINEAR, the GLOBAL source byte address is pre-swizzled with the involution
// byte ^= ((row&7)<<4), and the LDS read applies the same XOR. Each
// consecutive-8-lane group then hits 8 distinct 16B slots -> conflict-free.
//
// Fragment values and MFMA order are bit-identical to the passing round-2
// kernel; the accs scatter (unique-owner RMW, no atomics) is unchanged.
// Out stores are nontemporal (via clang ext-vector f32x4 — HIP float4 is a
// class type that __builtin_nontemporal_store rejects) so the 64 MB write
// stream stops evicting inner/f2t from L2/LLC.
__global__ __launch_bounds__(256) void k3_ffn2(const bf16* __restrict__ inner,
                                               const bf16* __restrict__ f2t,
                                               const unsigned* __restrict__ selp,
                                               float* __restrict__ out) {
    __shared__ float accs[512 * 32];                 // 64 KB
    __shared__ __align__(16) bf16 As[2][32 * 64];    // 8 KB (2 x 4 KB tiles)
    __shared__ __align__(16) bf16 Bs[2][32 * 64];    // 8 KB   -> 80 KB total, 2 blk/CU
    const int d0  = blockIdx.x * 32;
    const int g0  = blockIdx.y * 32;
    const int tid = threadIdx.x;
    const int w = tid >> 6, l = tid & 63, quad = l >> 4, lr = l & 15;
    const int mh = w >> 1, nh = w & 1;

    // preload sel nibbles: this lane's 4 rows x 64 es (8 dwords per row)
    unsigned sp[4][8];
    #pragma unroll
    for (int r = 0; r < 4; ++r) {
        int gl = mh * 16 + quad * 4 + r;
        uint4 a = *(const uint4*)(selp + (size_t)(g0 + gl) * 8);
        uint4 b = *(const uint4*)(selp + (size_t)(g0 + gl) * 8 + 4);
        sp[r][0] = a.x; sp[r][1] = a.y; sp[r][2] = a.z; sp[r][3] = a.w;
        sp[r][4] = b.x; sp[r][5] = b.y; sp[r][6] = b.z; sp[r][7] = b.w;
    }

    // staging source: lane owns tile byte tid*16 -> row tid>>3, in-row byte
    // (tid&7)*16, XOR-swizzled (inverse of the read swizzle; involution).
    const int srow = tid >> 3;
    const int scb  = ((tid & 7) * 16) ^ ((srow & 7) << 4);
    const bf16* srcA = inner + (size_t)(g0 + srow) * 64 + (scb >> 1);
    const bf16* srcB = f2t   + (size_t)(d0 + srow) * 64 + (scb >> 1);
    bf16* dA0 = &As[0][w * 512]; bf16* dA1 = &As[1][w * 512];
    bf16* dB0 = &Bs[0][w * 512]; bf16* dB1 = &Bs[1][w * 512];

    // zero accs
    #pragma unroll
    for (int i = 0; i < 16; ++i)
        ((f32x4*)accs)[i * 256 + tid] = (f32x4){0.f, 0.f, 0.f, 0.f};

    // prologue: stage es=0 into buffer 0
    gld_lds16(srcA, dA0);
    gld_lds16(srcB, dB0);
    __syncthreads();   // drains vmcnt: accs zeroed + stage(0) landed, all waves

    // fragment LDS byte offsets (swizzled), fixed per lane
    const int rowA = mh * 16 + lr, rowB = nh * 16 + lr;
    const int offA0 = rowA * 128 + ((quad * 16)      ^ ((rowA & 7) << 4));
    const int offA1 = rowA * 128 + ((quad * 16 + 64) ^ ((rowA & 7) << 4));
    const int offB0 = rowB * 128 + ((quad * 16)      ^ ((rowB & 7) << 4));
    const int offB1 = rowB * 128 + ((quad * 16 + 64) ^ ((rowB & 7) << 4));

    #pragma unroll
    for (int es = 0; es < 64; ++es) {
        const int cur = es & 1;
        // issue stage(es+1) into the other buffer; its last readers finished
        // before the trailing barrier of iteration es-1, so overwrite is safe
        if (es < 63) {
            if (cur == 0) { gld_lds16(srcA + (size_t)(es + 1) * 65536, dA1);
                            gld_lds16(srcB + (size_t)(es + 1) * 65536, dB1); }
            else          { gld_lds16(srcA + (size_t)(es + 1) * 65536, dA0);
                            gld_lds16(srcB + (size_t)(es + 1) * 65536, dB0); }
            asm volatile("s_waitcnt vmcnt(2)" ::: "memory");  // stage(es) done, 2 in flight
        } else {
            asm volatile("s_waitcnt vmcnt(0)" ::: "memory");  // final drain
        }
        asm volatile("s_barrier" ::: "memory");   // buf[cur] visible to all waves

        const char* a = (const char*)As[cur];
        const char* b = (const char*)Bs[cur];
        bf16x8 a0 = *(const bf16x8*)(a + offA0);
        bf16x8 a1 = *(const bf16x8*)(a + offA1);
        bf16x8 b0 = *(const bf16x8*)(b + offB0);
        bf16x8 b1 = *(const bf16x8*)(b + offB1);
        f32x4 z = {0.f, 0.f, 0.f, 0.f};
        z = __builtin_amdgcn_mfma_f32_16x16x32_bf16(a0, b0, z, 0, 0, 0);
        z = __builtin_amdgcn_mfma_f32_16x16x32_bf16(a1, b1, z, 0, 0, 0);

        const int dw = es >> 3, sh = (es & 7) * 4;   // compile-time after unroll
        #pragma unroll
        for (int r = 0; r < 4; ++r) {
            int t    = (sp[r][dw] >> sh) & 15;
            int gl   = mh * 16 + quad * 4 + r;
            int scol = (nh * 16 + lr) ^ ((t & 7) << 2);
            accs[(gl * 16 + t) * 32 + scol] += z[r];   // unique owner: no race
        }
        asm volatile("s_barrier" ::: "memory");   // all reads of buf[cur] done
    }
    __syncthreads();
    // dense write-out (un-swizzle; every output element written exactly once)
    #pragma unroll
    for (int i = 0; i < 16; ++i) {
        int fi = i * 256 + tid;
        int row = fi >> 3, q = fi & 7;
        int scol4 = (q * 4) ^ ((row & 7) << 2);
        f32x4 v = *(f32x4*)(accs + row * 32 + scol4);
        __builtin_nontemporal_store(v, (f32x4*)(out + (size_t)(g0 * 16 + row) * DM + d0 + q * 4));
    }
}

extern "C" void kernel_launch(void* const* d_in, const int* in_sizes, int n_in,
                              void* d_out, int out_size, void* d_ws, size_t ws_size,
                              hipStream_t stream) {
    const float* x    = (const float*)d_in[0];
    const float* ctrl = (const float*)d_in[1];
    const float* f1   = (const float*)d_in[2];
    const float* f2   = (const float*)d_in[3];
    const float* bias = (const float*)d_in[4];
    float* out = (float*)d_out;

    char* ws = (char*)d_ws;
    bf16*     f1p   = (bf16*)(ws);                  // 8,388,608 B
    bf16*     f2t   = (bf16*)(ws + 8388608);        // 8,388,608 B
    bf16*     inner = (bf16*)(ws + 16777216);       // 8,388,608 B
    int*      sel   = (int*)(ws + 25165824);        //   262,144 B
    unsigned* selp  = (unsigned*)(ws + 25427968);   //    32,768 B

    hipLaunchKernelGGL(k0_transpose, dim3(16, 64), dim3(256), 0, stream, f1, f2, f1p, f2t);
    hipLaunchKernelGGL(k1_logits,    dim3(1024),   dim3(256), 0, stream, x, ctrl, sel, selp);
    hipLaunchKernelGGL(k2_ffn1,      dim3(8, 64),  dim3(256), 0, stream, x, f1p, bias, sel, inner);
    hipLaunchKernelGGL(k3_ffn2,      dim3(32, 32), dim3(256), 0, stream, inner, f2t, selp, out);
}